// Round 3
// baseline (453.847 us; speedup 1.0000x reference)
//
#include <hip/hip_runtime.h>
#include <math.h>

// ---------------------------------------------------------------------------
// MultiLoss + JSD fused pipeline. R7:
//  * k_main ILP=2: each thread owns TWO rows (rowA, rowB=rowA+64) with
//    independent load->pin->compute chains, interleaved per window. R6 showed
//    the per-window volatile-asm pins produce a depth-~5 software pipeline
//    (VGPR stayed 52, 137->118us). Two independent chains double the loads
//    in flight per wave at the same pipeline depth. Grid halves to B/128.
//  * k_init launch DELETED: ws zero-init via hipMemsetAsync; MIN is stored
//    as max(~f2ord(v)) ("inverted order") so min/max/counts/hists/sums all
//    zero-init.
//  * hist chain unchanged from R6 (256-block coalesced LDS hist + skip-zero
//    atomic merge): non-k_main time didn't move across two redesigns
//    (R4 309us vs R6 325us) => dominated by fixed per-iteration cost, not
//    kernel math.
// ---------------------------------------------------------------------------

#define BINS 800
#define NHCOLS 10
#define HBLK 256          // histogram blocks (1 per CU)

// workspace layout (uint32 indices)
#define MIN_OFF 0         // 11 inverted-order maxes (== mins)
#define MAX_OFF 16        // 11 ordered-uint maxs
#define CNT_OFF 32        // male, female counts
#define MH_OFF  64        // 8000 merged male hist
#define FH_OFF  8064      // 8000 merged female hist
#define SUM2_OFF 16384    // 64 mse slots (stride 32) then 64 ce slots (stride 32)
#define SUM2_CE  (SUM2_OFF + 2048)
#define WS_TOTAL_U32 20480

__device__ __forceinline__ unsigned f2ord(float f) {
  unsigned u = __float_as_uint(f);
  return (u & 0x80000000u) ? ~u : (u | 0x80000000u);
}
__device__ __forceinline__ float ord2f(unsigned e) {
  return __uint_as_float((e & 0x80000000u) ? (e & 0x7FFFFFFFu) : ~e);
}

// per-column min/max of data_encoded + male/female counts from label.
// MIN stored as atomicMax of ~f2ord(v): zero-initializable.
__global__ __launch_bounds__(256) void k_minmax(const float* __restrict__ enc,
                                                const float* __restrict__ lab,
                                                unsigned* __restrict__ ws, int B) {
  const int tid    = blockIdx.x * blockDim.x + threadIdx.x;
  const int stride = gridDim.x * blockDim.x;   // 352*256 = 90112 = 11*8192
  const int c      = tid % 11;
  unsigned mni = 0u, mx = 0u;                  // mni: max of inverted order
  const long long total = (long long)B * 11;
  for (long long i = tid; i < total; i += stride) {
    unsigned e = f2ord(enc[i]);
    unsigned ei = ~e;
    mni = mni > ei ? mni : ei;
    mx  = mx  > e  ? mx  : e;
  }
  __shared__ unsigned smn[11], smx[11], scnt[2];
  if (threadIdx.x < 11) { smn[threadIdx.x] = 0u; smx[threadIdx.x] = 0u; }
  if (threadIdx.x < 2)  scnt[threadIdx.x] = 0u;
  __syncthreads();
  atomicMax(&smn[c], mni);
  atomicMax(&smx[c], mx);
  unsigned m = 0, f = 0;
  for (int i = tid; i < B; i += stride) {
    float v = lab[i];
    m += (v == 0.0f);
    f += (v == 1.0f);
  }
  atomicAdd(&scnt[0], m);
  atomicAdd(&scnt[1], f);
  __syncthreads();
  if (threadIdx.x < 11) {
    atomicMax(&ws[MIN_OFF + threadIdx.x], smn[threadIdx.x]);
    atomicMax(&ws[MAX_OFF + threadIdx.x], smx[threadIdx.x]);
  }
  if (threadIdx.x == 11) atomicAdd(&ws[CNT_OFF + 0], scnt[0]);
  if (threadIdx.x == 12) atomicAdd(&ws[CNT_OFF + 1], scnt[1]);
}

// gendered histograms, male packed lo16 / female hi16 in per-block LDS hist
// (per-block per-bin count <= B/HBLK = 1024, fits 16 bits), merged into
// global MH/FH with skip-zero atomics. Element-linear grid-stride: lane i
// reads enc word i (fully coalesced); (r,c) updated incrementally.
__global__ __launch_bounds__(256) void k_hist(const float* __restrict__ enc,
                                              const float* __restrict__ lab,
                                              unsigned* __restrict__ ws, int B) {
  __shared__ unsigned h[2][NHCOLS * BINS];
  __shared__ float smn[NHCOLS], srng[NHCOLS];
  unsigned* hf = &h[0][0];
  for (int i = threadIdx.x; i < 2 * NHCOLS * BINS; i += blockDim.x) hf[i] = 0u;
  if (threadIdx.x < NHCOLS) {
    float lo = ord2f(~ws[MIN_OFF + threadIdx.x]);   // inverted-order min
    float hi = ord2f(ws[MAX_OFF + threadIdx.x]);
    smn[threadIdx.x] = lo;
    srng[threadIdx.x] = hi - lo;
  }
  __syncthreads();
  const int sub    = (threadIdx.x >> 6) & 1;
  const int total  = B * 11;
  const int stride = HBLK * 256;               // 65536
  const int qs     = stride / 11;              // uniform
  const int rs     = stride % 11;
  int i = blockIdx.x * 256 + threadIdx.x;
  int r = i / 11;                              // one div total
  int c = i - r * 11;
  for (; i < total; i += stride) {
    if (c < NHCOLS) {
      float lv = lab[r];
      unsigned add = (lv == 0.0f) ? 1u : ((lv == 1.0f) ? 0x10000u : 0u);
      if (add) {
        float t = (enc[i] - smn[c]) / srng[c]; // IEEE div, matches numpy
        int b = (int)floorf(t * 800.0f);
        b = b < 0 ? 0 : (b > BINS - 1 ? BINS - 1 : b);
        atomicAdd(&h[sub][c * BINS + b], add);
      }
    }
    r += qs; c += rs;
    if (c >= 11) { c -= 11; ++r; }
  }
  __syncthreads();
  for (int k = threadIdx.x; k < NHCOLS * BINS; k += blockDim.x) {
    unsigned v = h[0][k] + h[1][k];
    unsigned m = v & 0xFFFFu, f = v >> 16;
    if (m) atomicAdd(&ws[MH_OFF + k], m);
    if (f) atomicAdd(&ws[FH_OFF + k], f);
  }
}

// ---- column classification (compile-time) ----
__host__ __device__ constexpr int slice_of(int c) {
  return (c>=1&&c<10)?0:(c>=12&&c<29)?1:(c>=30&&c<33)?2:(c>=33&&c<40)?3:
         (c>=40&&c<64)?4:(c>=64&&c<79)?5:(c>=79&&c<84)?6:(c>=84&&c<94)?7:
         (c>=94&&c<96)?8:(c>=96&&c<99)?9:(c>=99&&c<105)?10:(c>=105&&c<113)?11:
         (c>=116&&c<122)?12:(c>=122&&c<128)?13:(c>=128&&c<151)?14:
         (c>=151&&c<159)?15:(c>=160&&c<165)?16:-1;
}
__host__ __device__ constexpr bool mse_of(int c) {
  return c==0||c==10||c==11||c==29||c==113||c==114||c==115||c==159||
         c==165||c==166||c==167;
}

// One register element (window I, sub-elem K). Lane j of the quad holds
// column 16I+4j+K; masks over j are compile-time -> branchless cndmask+add.
template<int I, int K>
__device__ __forceinline__ void elem(const float (&d)[11][4], const float (&t)[11][4],
                                     float (&s)[17], float &dot, float &mse, int j) {
  constexpr int c0 = 16*I + K, c1 = c0+4, c2 = c0+8, c3 = c0+12;
  constexpr int cem = ((c0<168 && slice_of(c0)>=0)?1:0) |
                      ((c1<168 && slice_of(c1)>=0)?2:0) |
                      ((c2<168 && slice_of(c2)>=0)?4:0) |
                      ((c3<168 && slice_of(c3)>=0)?8:0);
  constexpr int msm = ((c0<168 && mse_of(c0))?1:0) | ((c1<168 && mse_of(c1))?2:0) |
                      ((c2<168 && mse_of(c2))?4:0) | ((c3<168 && mse_of(c3))?8:0);
  const float dv = d[I][K], tv = t[I][K];
  if constexpr (cem != 0) {
    float e = __expf(dv);
    if constexpr (cem & 1) s[slice_of(c0)] += (j == 0) ? e : 0.0f;
    if constexpr (cem & 2) s[slice_of(c1)] += (j == 1) ? e : 0.0f;
    if constexpr (cem & 4) s[slice_of(c2)] += (j == 2) ? e : 0.0f;
    if constexpr (cem & 8) s[slice_of(c3)] += (j == 3) ? e : 0.0f;
    dot += ((cem >> j) & 1) ? tv * dv : 0.0f;
  }
  if constexpr (msm != 0) {
    float df = dv - tv;
    mse += ((msm >> j) & 1) ? df * df : 0.0f;
  }
}

template<int I>
__device__ __forceinline__ void elem_row(const float (&d)[11][4], const float (&t)[11][4],
                                         float (&s)[17], float &dot, float &mse, int j) {
  elem<I,0>(d, t, s, dot, mse, j);
  elem<I,1>(d, t, s, dot, mse, j);
  elem<I,2>(d, t, s, dot, mse, j);
  elem<I,3>(d, t, s, dot, mse, j);
}

// quad-per-row, TWO rows per thread (A: block rows 0..63, B: rows 64..127).
// Lane j of the quad loads words 4i+j of each row (64B contiguous per quad
// per window). All loads unconditional (row clamped to B-1, word clamped to
// 41; duplicates never accumulated -- compile-time cem/msm masks are zero
// there, invalid rows masked at the end). Per-window volatile-asm pins keep
// the loads from sinking to their uses; with two independent chains the
// scheduler's depth-~5 pipeline carries ~2x loads in flight.
__global__ __launch_bounds__(256, 3) void k_main(const float* __restrict__ dec,
                                                 const float* __restrict__ tru,
                                                 float* __restrict__ wsf, int B) {
  const int lane = threadIdx.x & 63;
  const int wid  = threadIdx.x >> 6;
  const int j    = lane & 3;
  const int rowA = blockIdx.x * 128 + (wid << 4) + (lane >> 2);
  const int rowB = rowA + 64;
  const bool validA = rowA < B;
  const bool validB = rowB < B;
  const int rA = validA ? rowA : (B - 1);
  const int rB = validB ? rowB : (B - 1);

  float dA[11][4], tA[11][4], dB[11][4], tB[11][4];
  const float4* dA4 = (const float4*)(dec + (size_t)rA * 168);
  const float4* tA4 = (const float4*)(tru + (size_t)rA * 168);
  const float4* dB4 = (const float4*)(dec + (size_t)rB * 168);
  const float4* tB4 = (const float4*)(tru + (size_t)rB * 168);
#pragma unroll
  for (int i = 0; i < 11; ++i) {
    int w = 4 * i + j;
    w = w > 41 ? 41 : w;                 // j>=2 of window 10: dup load, never used
    const float4 av = dA4[w];
    const float4 aw = tA4[w];
    const float4 bv = dB4[w];
    const float4 bw = tB4[w];
    dA[i][0] = av.x; dA[i][1] = av.y; dA[i][2] = av.z; dA[i][3] = av.w;
    tA[i][0] = aw.x; tA[i][1] = aw.y; tA[i][2] = aw.z; tA[i][3] = aw.w;
    dB[i][0] = bv.x; dB[i][1] = bv.y; dB[i][2] = bv.z; dB[i][3] = bv.w;
    tB[i][0] = bw.x; tB[i][1] = bw.y; tB[i][2] = bw.z; tB[i][3] = bw.w;
    asm volatile("" : "+v"(dA[i][0]), "+v"(dA[i][1]), "+v"(dA[i][2]), "+v"(dA[i][3]),
                      "+v"(tA[i][0]), "+v"(tA[i][1]), "+v"(tA[i][2]), "+v"(tA[i][3]),
                      "+v"(dB[i][0]), "+v"(dB[i][1]), "+v"(dB[i][2]), "+v"(dB[i][3]),
                      "+v"(tB[i][0]), "+v"(tB[i][1]), "+v"(tB[i][2]), "+v"(tB[i][3]));
  }

  float sA[17], sB[17];
#pragma unroll
  for (int k = 0; k < 17; ++k) { sA[k] = 0.0f; sB[k] = 0.0f; }
  float dotA = 0.0f, mseA = 0.0f, dotB = 0.0f, mseB = 0.0f;

  elem_row<0>(dA, tA, sA, dotA, mseA, j);  elem_row<0>(dB, tB, sB, dotB, mseB, j);
  elem_row<1>(dA, tA, sA, dotA, mseA, j);  elem_row<1>(dB, tB, sB, dotB, mseB, j);
  elem_row<2>(dA, tA, sA, dotA, mseA, j);  elem_row<2>(dB, tB, sB, dotB, mseB, j);
  elem_row<3>(dA, tA, sA, dotA, mseA, j);  elem_row<3>(dB, tB, sB, dotB, mseB, j);
  elem_row<4>(dA, tA, sA, dotA, mseA, j);  elem_row<4>(dB, tB, sB, dotB, mseB, j);
  elem_row<5>(dA, tA, sA, dotA, mseA, j);  elem_row<5>(dB, tB, sB, dotB, mseB, j);
  elem_row<6>(dA, tA, sA, dotA, mseA, j);  elem_row<6>(dB, tB, sB, dotB, mseB, j);
  elem_row<7>(dA, tA, sA, dotA, mseA, j);  elem_row<7>(dB, tB, sB, dotB, mseB, j);
  elem_row<8>(dA, tA, sA, dotA, mseA, j);  elem_row<8>(dB, tB, sB, dotB, mseB, j);
  elem_row<9>(dA, tA, sA, dotA, mseA, j);  elem_row<9>(dB, tB, sB, dotB, mseB, j);
  elem_row<10>(dA, tA, sA, dotA, mseA, j); elem_row<10>(dB, tB, sB, dotB, mseB, j);

  // quad allreduce: independent shuffles
  dotA += __shfl_xor(dotA, 1, 64);
  dotA += __shfl_xor(dotA, 2, 64);
  dotB += __shfl_xor(dotB, 1, 64);
  dotB += __shfl_xor(dotB, 2, 64);
#pragma unroll
  for (int k = 0; k < 17; ++k) {
    sA[k] += __shfl_xor(sA[k], 1, 64);
    sA[k] += __shfl_xor(sA[k], 2, 64);
    sB[k] += __shfl_xor(sB[k], 1, 64);
    sB[k] += __shfl_xor(sB[k], 2, 64);
  }
  float ceA = -dotA, ceB = -dotB;
#pragma unroll
  for (int k = 0; k < 17; ++k) { ceA += __logf(sA[k]); ceB += __logf(sB[k]); }

  // ce replicated across quad -> count once; mask invalid rows.
  float ce  = ((validA && j == 0) ? ceA : 0.0f) + ((validB && j == 0) ? ceB : 0.0f);
  float mse = (validA ? mseA : 0.0f) + (validB ? mseB : 0.0f);

  __shared__ float sm[4], sc[4];
#pragma unroll
  for (int off = 32; off > 0; off >>= 1) {
    mse += __shfl_down(mse, off, 64);
    ce  += __shfl_down(ce, off, 64);
  }
  if (lane == 0) { sm[wid] = mse; sc[wid] = ce; }
  __syncthreads();
  if (threadIdx.x == 0) {
    const int slot = (blockIdx.x & 63) * 32;   // 128B-padded slots, 64-way spread
    atomicAdd(&wsf[SUM2_OFF + slot], sm[0] + sm[1] + sm[2] + sm[3]);
    atomicAdd(&wsf[SUM2_CE  + slot], sc[0] + sc[1] + sc[2] + sc[3]);
  }
}

__global__ __launch_bounds__(256) void k_final(const unsigned* __restrict__ ws,
                                               float* __restrict__ out, int B) {
  const float* wsf = (const float*)ws;
  float male   = (float)ws[CNT_OFF + 0];
  float female = (float)ws[CNT_OFF + 1];
  float local = 0.0f;
  for (int i = threadIdx.x; i < NHCOLS * BINS; i += blockDim.x) {
    float mh  = (float)ws[MH_OFF + i] / male;
    float fh  = (float)ws[FH_OFF + i] / female;
    float mid = 0.5f * (mh + fh);
    if (mh > 0.0f) local += mh * logf((mh + 1e-12f) / (mid + 1e-12f));
    if (fh > 0.0f) local += fh * logf((fh + 1e-12f) / (mid + 1e-12f));
  }
  int lane = threadIdx.x & 63, wid = threadIdx.x >> 6;
  // mse/ce staging slots: wave 0 reduces 64 slots in parallel
  float msep = 0.0f, cep = 0.0f;
  if (threadIdx.x < 64) {
    msep = wsf[SUM2_OFF + threadIdx.x * 32];
    cep  = wsf[SUM2_CE  + threadIdx.x * 32];
  }
  __shared__ float s[4], sm2, sc2;
#pragma unroll
  for (int off = 32; off > 0; off >>= 1) {
    local += __shfl_down(local, off, 64);
    msep  += __shfl_down(msep, off, 64);
    cep   += __shfl_down(cep, off, 64);
  }
  if (lane == 0) s[wid] = local;
  if (threadIdx.x == 0) { sm2 = msep; sc2 = cep; }
  __syncthreads();
  if (threadIdx.x == 0) {
    float kld   = 0.5f * (s[0] + s[1] + s[2] + s[3]);
    float mse   = sm2 / (float)B;
    float ce    = sc2 / (float)B;
    float multi = 0.9f * (mse + ce) + 0.1f * kld;
    out[0] = multi;
    out[1] = mse;
    out[2] = ce;
    out[3] = 0.1f * kld;
  }
}

extern "C" void kernel_launch(void* const* d_in, const int* in_sizes, int n_in,
                              void* d_out, int out_size, void* d_ws, size_t ws_size,
                              hipStream_t stream) {
  (void)n_in; (void)out_size; (void)ws_size;
  const float* enc = (const float*)d_in[0];
  const float* dec = (const float*)d_in[1];
  const float* tru = (const float*)d_in[2];
  const float* lab = (const float*)d_in[3];
  const int B = in_sizes[3];                 // label_true is [B,1]
  unsigned* ws = (unsigned*)d_ws;
  float* out = (float*)d_out;

  hipMemsetAsync(ws, 0, WS_TOTAL_U32 * 4, stream);   // replaces k_init launch
  hipLaunchKernelGGL(k_minmax, dim3(352), dim3(256), 0, stream, enc, lab, ws, B);
  hipLaunchKernelGGL(k_hist, dim3(HBLK), dim3(256), 0, stream, enc, lab, ws, B);
  hipLaunchKernelGGL(k_main, dim3((B + 127) / 128), dim3(256), 0, stream,
                     dec, tru, (float*)ws, B);
  hipLaunchKernelGGL(k_final, dim3(1), dim3(256), 0, stream, ws, out, B);
}

// Round 4
// 443.130 us; speedup vs baseline: 1.0242x; 1.0242x over previous
//
#include <hip/hip_runtime.h>
#include <math.h>

// ---------------------------------------------------------------------------
// MultiLoss + JSD fused pipeline. R8:
//  * k_main: back to 1 row/thread (R7's ILP=2 halved blocks and grew
//    FETCH_SIZE 172->264 MB: lost inter-iteration L3 retention; net loss).
//    Loads are now INLINE-ASM global_load_dwordx4: volatile asm cannot be
//    sunk by the compiler, so all 22 loads issue back-to-back and ~88 data
//    VGPRs are forced live (R5 sched_barrier and R6/R7 pin attempts all
//    failed to beat the register allocator: VGPR stuck at 52-60, pipeline
//    depth ~5). One base addr per array + offset:64*i immediates (i=0..9);
//    window 10 has a per-lane clamped address (word min(40+j,41)) matching
//    the old w>41 clamp and staying in-bounds. s_waitcnt vmcnt(0) +
//    sched_barrier(0) + re-pin orders compute after data arrival (rule:
//    consumers depend on the post-wait pin, which is volatile-ordered after
//    the waitcnt). __launch_bounds__(256,2): room for ~130 VGPR, no spill;
//    16 waves/CU x 22 loads in flight => latency fully hidden.
//  * others (~320us) pinned across R4/R6/R7 despite launch-count changes:
//    harness-fixed cost. Left untouched.
// ---------------------------------------------------------------------------

#define BINS 800
#define NHCOLS 10
#define HBLK 256          // histogram blocks (1 per CU)

// workspace layout (uint32 indices)
#define MIN_OFF 0         // 11 inverted-order maxes (== mins)
#define MAX_OFF 16        // 11 ordered-uint maxs
#define CNT_OFF 32        // male, female counts
#define MH_OFF  64        // 8000 merged male hist
#define FH_OFF  8064      // 8000 merged female hist
#define SUM2_OFF 16384    // 64 mse slots (stride 32) then 64 ce slots (stride 32)
#define SUM2_CE  (SUM2_OFF + 2048)
#define WS_TOTAL_U32 20480

typedef float f4 __attribute__((ext_vector_type(4)));

__device__ __forceinline__ unsigned f2ord(float f) {
  unsigned u = __float_as_uint(f);
  return (u & 0x80000000u) ? ~u : (u | 0x80000000u);
}
__device__ __forceinline__ float ord2f(unsigned e) {
  return __uint_as_float((e & 0x80000000u) ? (e & 0x7FFFFFFFu) : ~e);
}

// per-column min/max of data_encoded + male/female counts from label.
// MIN stored as atomicMax of ~f2ord(v): zero-initializable.
__global__ __launch_bounds__(256) void k_minmax(const float* __restrict__ enc,
                                                const float* __restrict__ lab,
                                                unsigned* __restrict__ ws, int B) {
  const int tid    = blockIdx.x * blockDim.x + threadIdx.x;
  const int stride = gridDim.x * blockDim.x;   // 352*256 = 90112 = 11*8192
  const int c      = tid % 11;
  unsigned mni = 0u, mx = 0u;                  // mni: max of inverted order
  const long long total = (long long)B * 11;
  for (long long i = tid; i < total; i += stride) {
    unsigned e = f2ord(enc[i]);
    unsigned ei = ~e;
    mni = mni > ei ? mni : ei;
    mx  = mx  > e  ? mx  : e;
  }
  __shared__ unsigned smn[11], smx[11], scnt[2];
  if (threadIdx.x < 11) { smn[threadIdx.x] = 0u; smx[threadIdx.x] = 0u; }
  if (threadIdx.x < 2)  scnt[threadIdx.x] = 0u;
  __syncthreads();
  atomicMax(&smn[c], mni);
  atomicMax(&smx[c], mx);
  unsigned m = 0, f = 0;
  for (int i = tid; i < B; i += stride) {
    float v = lab[i];
    m += (v == 0.0f);
    f += (v == 1.0f);
  }
  atomicAdd(&scnt[0], m);
  atomicAdd(&scnt[1], f);
  __syncthreads();
  if (threadIdx.x < 11) {
    atomicMax(&ws[MIN_OFF + threadIdx.x], smn[threadIdx.x]);
    atomicMax(&ws[MAX_OFF + threadIdx.x], smx[threadIdx.x]);
  }
  if (threadIdx.x == 11) atomicAdd(&ws[CNT_OFF + 0], scnt[0]);
  if (threadIdx.x == 12) atomicAdd(&ws[CNT_OFF + 1], scnt[1]);
}

// gendered histograms, male packed lo16 / female hi16 in per-block LDS hist
// (per-block per-bin count <= B/HBLK = 1024, fits 16 bits), merged into
// global MH/FH with skip-zero atomics. Element-linear grid-stride: lane i
// reads enc word i (fully coalesced); (r,c) updated incrementally.
__global__ __launch_bounds__(256) void k_hist(const float* __restrict__ enc,
                                              const float* __restrict__ lab,
                                              unsigned* __restrict__ ws, int B) {
  __shared__ unsigned h[2][NHCOLS * BINS];
  __shared__ float smn[NHCOLS], srng[NHCOLS];
  unsigned* hf = &h[0][0];
  for (int i = threadIdx.x; i < 2 * NHCOLS * BINS; i += blockDim.x) hf[i] = 0u;
  if (threadIdx.x < NHCOLS) {
    float lo = ord2f(~ws[MIN_OFF + threadIdx.x]);   // inverted-order min
    float hi = ord2f(ws[MAX_OFF + threadIdx.x]);
    smn[threadIdx.x] = lo;
    srng[threadIdx.x] = hi - lo;
  }
  __syncthreads();
  const int sub    = (threadIdx.x >> 6) & 1;
  const int total  = B * 11;
  const int stride = HBLK * 256;               // 65536
  const int qs     = stride / 11;              // uniform
  const int rs     = stride % 11;
  int i = blockIdx.x * 256 + threadIdx.x;
  int r = i / 11;                              // one div total
  int c = i - r * 11;
  for (; i < total; i += stride) {
    if (c < NHCOLS) {
      float lv = lab[r];
      unsigned add = (lv == 0.0f) ? 1u : ((lv == 1.0f) ? 0x10000u : 0u);
      if (add) {
        float t = (enc[i] - smn[c]) / srng[c]; // IEEE div, matches numpy
        int b = (int)floorf(t * 800.0f);
        b = b < 0 ? 0 : (b > BINS - 1 ? BINS - 1 : b);
        atomicAdd(&h[sub][c * BINS + b], add);
      }
    }
    r += qs; c += rs;
    if (c >= 11) { c -= 11; ++r; }
  }
  __syncthreads();
  for (int k = threadIdx.x; k < NHCOLS * BINS; k += blockDim.x) {
    unsigned v = h[0][k] + h[1][k];
    unsigned m = v & 0xFFFFu, f = v >> 16;
    if (m) atomicAdd(&ws[MH_OFF + k], m);
    if (f) atomicAdd(&ws[FH_OFF + k], f);
  }
}

// ---- column classification (compile-time) ----
__host__ __device__ constexpr int slice_of(int c) {
  return (c>=1&&c<10)?0:(c>=12&&c<29)?1:(c>=30&&c<33)?2:(c>=33&&c<40)?3:
         (c>=40&&c<64)?4:(c>=64&&c<79)?5:(c>=79&&c<84)?6:(c>=84&&c<94)?7:
         (c>=94&&c<96)?8:(c>=96&&c<99)?9:(c>=99&&c<105)?10:(c>=105&&c<113)?11:
         (c>=116&&c<122)?12:(c>=122&&c<128)?13:(c>=128&&c<151)?14:
         (c>=151&&c<159)?15:(c>=160&&c<165)?16:-1;
}
__host__ __device__ constexpr bool mse_of(int c) {
  return c==0||c==10||c==11||c==29||c==113||c==114||c==115||c==159||
         c==165||c==166||c==167;
}

// One register element (window I, sub-elem K). Lane j of the quad holds
// column 16I+4j+K; masks over j are compile-time -> branchless cndmask+add.
template<int I, int K>
__device__ __forceinline__ void elem(const f4 (&d)[11], const f4 (&t)[11],
                                     float (&s)[17], float &dot, float &mse, int j) {
  constexpr int c0 = 16*I + K, c1 = c0+4, c2 = c0+8, c3 = c0+12;
  constexpr int cem = ((c0<168 && slice_of(c0)>=0)?1:0) |
                      ((c1<168 && slice_of(c1)>=0)?2:0) |
                      ((c2<168 && slice_of(c2)>=0)?4:0) |
                      ((c3<168 && slice_of(c3)>=0)?8:0);
  constexpr int msm = ((c0<168 && mse_of(c0))?1:0) | ((c1<168 && mse_of(c1))?2:0) |
                      ((c2<168 && mse_of(c2))?4:0) | ((c3<168 && mse_of(c3))?8:0);
  const float dv = d[I][K], tv = t[I][K];
  if constexpr (cem != 0) {
    float e = __expf(dv);
    if constexpr (cem & 1) s[slice_of(c0)] += (j == 0) ? e : 0.0f;
    if constexpr (cem & 2) s[slice_of(c1)] += (j == 1) ? e : 0.0f;
    if constexpr (cem & 4) s[slice_of(c2)] += (j == 2) ? e : 0.0f;
    if constexpr (cem & 8) s[slice_of(c3)] += (j == 3) ? e : 0.0f;
    dot += ((cem >> j) & 1) ? tv * dv : 0.0f;
  }
  if constexpr (msm != 0) {
    float df = dv - tv;
    mse += ((msm >> j) & 1) ? df * df : 0.0f;
  }
}

template<int I>
__device__ __forceinline__ void elem_row(const f4 (&d)[11], const f4 (&t)[11],
                                         float (&s)[17], float &dot, float &mse, int j) {
  elem<I,0>(d, t, s, dot, mse, j);
  elem<I,1>(d, t, s, dot, mse, j);
  elem<I,2>(d, t, s, dot, mse, j);
  elem<I,3>(d, t, s, dot, mse, j);
}

// Two asm loads (window idx, byte offset off) off the shared bases.
#define LD2(idx, off)                                                          \
  asm volatile("global_load_dwordx4 %0, %1, off offset:" #off                  \
               : "=v"(dv[idx]) : "v"(baseD));                                  \
  asm volatile("global_load_dwordx4 %0, %1, off offset:" #off                  \
               : "=v"(tv[idx]) : "v"(baseT));

// quad-per-row: lane j of the quad loads words 4i+j (64B contiguous per quad
// per window). All 22 loads are volatile inline-asm global_load_dwordx4:
// un-sinkable, so they issue back-to-back and stay in flight together.
// Windows 0..9 share one base (row*168+4j floats) + offset:64*i immediates;
// window 10 uses a per-lane clamped address (word min(40+j,41)): j>=2 is a
// duplicate whose cem/msm mask bits are compile-time zero -> never used.
__global__ __launch_bounds__(256, 2) void k_main(const float* __restrict__ dec,
                                                 const float* __restrict__ tru,
                                                 float* __restrict__ wsf, int B) {
  const int lane = threadIdx.x & 63;
  const int wid  = threadIdx.x >> 6;
  const int j    = lane & 3;
  const int row  = blockIdx.x * 64 + (wid << 4) + (lane >> 2);
  const bool valid = row < B;
  const int rowc = valid ? row : (B - 1);

  const float* baseD = dec + (size_t)rowc * 168 + 4 * j;
  const float* baseT = tru + (size_t)rowc * 168 + 4 * j;
  const int w10 = (40 + j) > 41 ? 41 : (40 + j);        // clamped last word
  const float* d10 = dec + (size_t)rowc * 168 + 4 * w10;
  const float* t10 = tru + (size_t)rowc * 168 + 4 * w10;

  f4 dv[11], tv[11];
  LD2(0, 0)
  LD2(1, 64)
  LD2(2, 128)
  LD2(3, 192)
  LD2(4, 256)
  LD2(5, 320)
  LD2(6, 384)
  LD2(7, 448)
  LD2(8, 512)
  LD2(9, 576)
  asm volatile("global_load_dwordx4 %0, %1, off" : "=v"(dv[10]) : "v"(d10));
  asm volatile("global_load_dwordx4 %0, %1, off" : "=v"(tv[10]) : "v"(t10));

  asm volatile("s_waitcnt vmcnt(0)" ::: "memory");
  __builtin_amdgcn_sched_barrier(0);
  // Re-pin after the wait: consumers depend on these (volatile-ordered after
  // the waitcnt), so no compute can be hoisted above data arrival.
#pragma unroll
  for (int i = 0; i < 11; ++i) asm volatile("" : "+v"(dv[i]), "+v"(tv[i]));

  float s[17];
#pragma unroll
  for (int k = 0; k < 17; ++k) s[k] = 0.0f;
  float dot = 0.0f, mse = 0.0f;

  elem_row<0>(dv, tv, s, dot, mse, j);
  elem_row<1>(dv, tv, s, dot, mse, j);
  elem_row<2>(dv, tv, s, dot, mse, j);
  elem_row<3>(dv, tv, s, dot, mse, j);
  elem_row<4>(dv, tv, s, dot, mse, j);
  elem_row<5>(dv, tv, s, dot, mse, j);
  elem_row<6>(dv, tv, s, dot, mse, j);
  elem_row<7>(dv, tv, s, dot, mse, j);
  elem_row<8>(dv, tv, s, dot, mse, j);
  elem_row<9>(dv, tv, s, dot, mse, j);
  elem_row<10>(dv, tv, s, dot, mse, j);

  // quad allreduce: 34 + 2 independent shuffles
  dot += __shfl_xor(dot, 1, 64);
  dot += __shfl_xor(dot, 2, 64);
#pragma unroll
  for (int k = 0; k < 17; ++k) {
    s[k] += __shfl_xor(s[k], 1, 64);
    s[k] += __shfl_xor(s[k], 2, 64);
  }
  float ce = -dot;
#pragma unroll
  for (int k = 0; k < 17; ++k) ce += __logf(s[k]);

  // ce replicated across quad -> count once; mask invalid rows.
  ce  = (valid && j == 0) ? ce : 0.0f;
  mse = valid ? mse : 0.0f;

  __shared__ float sm[4], sc[4];
#pragma unroll
  for (int off = 32; off > 0; off >>= 1) {
    mse += __shfl_down(mse, off, 64);
    ce  += __shfl_down(ce, off, 64);
  }
  if (lane == 0) { sm[wid] = mse; sc[wid] = ce; }
  __syncthreads();
  if (threadIdx.x == 0) {
    const int slot = (blockIdx.x & 63) * 32;   // 128B-padded slots, 64-way spread
    atomicAdd(&wsf[SUM2_OFF + slot], sm[0] + sm[1] + sm[2] + sm[3]);
    atomicAdd(&wsf[SUM2_CE  + slot], sc[0] + sc[1] + sc[2] + sc[3]);
  }
}

__global__ __launch_bounds__(256) void k_final(const unsigned* __restrict__ ws,
                                               float* __restrict__ out, int B) {
  const float* wsf = (const float*)ws;
  float male   = (float)ws[CNT_OFF + 0];
  float female = (float)ws[CNT_OFF + 1];
  float local = 0.0f;
  for (int i = threadIdx.x; i < NHCOLS * BINS; i += blockDim.x) {
    float mh  = (float)ws[MH_OFF + i] / male;
    float fh  = (float)ws[FH_OFF + i] / female;
    float mid = 0.5f * (mh + fh);
    if (mh > 0.0f) local += mh * logf((mh + 1e-12f) / (mid + 1e-12f));
    if (fh > 0.0f) local += fh * logf((fh + 1e-12f) / (mid + 1e-12f));
  }
  int lane = threadIdx.x & 63, wid = threadIdx.x >> 6;
  // mse/ce staging slots: wave 0 reduces 64 slots in parallel
  float msep = 0.0f, cep = 0.0f;
  if (threadIdx.x < 64) {
    msep = wsf[SUM2_OFF + threadIdx.x * 32];
    cep  = wsf[SUM2_CE  + threadIdx.x * 32];
  }
  __shared__ float s[4], sm2, sc2;
#pragma unroll
  for (int off = 32; off > 0; off >>= 1) {
    local += __shfl_down(local, off, 64);
    msep  += __shfl_down(msep, off, 64);
    cep   += __shfl_down(cep, off, 64);
  }
  if (lane == 0) s[wid] = local;
  if (threadIdx.x == 0) { sm2 = msep; sc2 = cep; }
  __syncthreads();
  if (threadIdx.x == 0) {
    float kld   = 0.5f * (s[0] + s[1] + s[2] + s[3]);
    float mse   = sm2 / (float)B;
    float ce    = sc2 / (float)B;
    float multi = 0.9f * (mse + ce) + 0.1f * kld;
    out[0] = multi;
    out[1] = mse;
    out[2] = ce;
    out[3] = 0.1f * kld;
  }
}

extern "C" void kernel_launch(void* const* d_in, const int* in_sizes, int n_in,
                              void* d_out, int out_size, void* d_ws, size_t ws_size,
                              hipStream_t stream) {
  (void)n_in; (void)out_size; (void)ws_size;
  const float* enc = (const float*)d_in[0];
  const float* dec = (const float*)d_in[1];
  const float* tru = (const float*)d_in[2];
  const float* lab = (const float*)d_in[3];
  const int B = in_sizes[3];                 // label_true is [B,1]
  unsigned* ws = (unsigned*)d_ws;
  float* out = (float*)d_out;

  hipMemsetAsync(ws, 0, WS_TOTAL_U32 * 4, stream);
  hipLaunchKernelGGL(k_minmax, dim3(352), dim3(256), 0, stream, enc, lab, ws, B);
  hipLaunchKernelGGL(k_hist, dim3(HBLK), dim3(256), 0, stream, enc, lab, ws, B);
  hipLaunchKernelGGL(k_main, dim3((B + 63) / 64), dim3(256), 0, stream,
                     dec, tru, (float*)ws, B);
  hipLaunchKernelGGL(k_final, dim3(1), dim3(256), 0, stream, ws, out, B);
}

// Round 5
// 439.380 us; speedup vs baseline: 1.0329x; 1.0085x over previous
//
#include <hip/hip_runtime.h>
#include <math.h>

// ---------------------------------------------------------------------------
// MultiLoss + JSD fused pipeline. R9:
//  * k_main: COUNTED-VMCNT INTERLEAVE. R6/R7/R8 all converge to ~118us with
//    VALU 19%, HBM 18%: each wave is [issue+drain (no VALU)] then [compute
//    (no outstanding loads)] -- latency-bound with avg outstanding ~47
//    lines/CU (copy ubench sustains 3-7x). Loads retire IN ISSUE ORDER
//    (vmcnt is FIFO), and elem_row<I> consumes only window I's two quads,
//    so: wait vmcnt(20-2I) -> pin window I -> compute window I. Each wave's
//    compute now runs while its remaining loads are in flight; requests stay
//    outstanding through the compute phase.
//  * loads identical to R8 (volatile asm global_load_dwordx4, base+offset
//    immediates, clamped window 10); accumulator init hoisted above loads.
//  * others (~320us) pinned across R4/R6/R7/R8: harness-fixed cost; untouched.
// ---------------------------------------------------------------------------

#define BINS 800
#define NHCOLS 10
#define HBLK 256          // histogram blocks (1 per CU)

// workspace layout (uint32 indices)
#define MIN_OFF 0         // 11 inverted-order maxes (== mins)
#define MAX_OFF 16        // 11 ordered-uint maxs
#define CNT_OFF 32        // male, female counts
#define MH_OFF  64        // 8000 merged male hist
#define FH_OFF  8064      // 8000 merged female hist
#define SUM2_OFF 16384    // 64 mse slots (stride 32) then 64 ce slots (stride 32)
#define SUM2_CE  (SUM2_OFF + 2048)
#define WS_TOTAL_U32 20480

typedef float f4 __attribute__((ext_vector_type(4)));

__device__ __forceinline__ unsigned f2ord(float f) {
  unsigned u = __float_as_uint(f);
  return (u & 0x80000000u) ? ~u : (u | 0x80000000u);
}
__device__ __forceinline__ float ord2f(unsigned e) {
  return __uint_as_float((e & 0x80000000u) ? (e & 0x7FFFFFFFu) : ~e);
}

// per-column min/max of data_encoded + male/female counts from label.
// MIN stored as atomicMax of ~f2ord(v): zero-initializable.
__global__ __launch_bounds__(256) void k_minmax(const float* __restrict__ enc,
                                                const float* __restrict__ lab,
                                                unsigned* __restrict__ ws, int B) {
  const int tid    = blockIdx.x * blockDim.x + threadIdx.x;
  const int stride = gridDim.x * blockDim.x;   // 352*256 = 90112 = 11*8192
  const int c      = tid % 11;
  unsigned mni = 0u, mx = 0u;                  // mni: max of inverted order
  const long long total = (long long)B * 11;
  for (long long i = tid; i < total; i += stride) {
    unsigned e = f2ord(enc[i]);
    unsigned ei = ~e;
    mni = mni > ei ? mni : ei;
    mx  = mx  > e  ? mx  : e;
  }
  __shared__ unsigned smn[11], smx[11], scnt[2];
  if (threadIdx.x < 11) { smn[threadIdx.x] = 0u; smx[threadIdx.x] = 0u; }
  if (threadIdx.x < 2)  scnt[threadIdx.x] = 0u;
  __syncthreads();
  atomicMax(&smn[c], mni);
  atomicMax(&smx[c], mx);
  unsigned m = 0, f = 0;
  for (int i = tid; i < B; i += stride) {
    float v = lab[i];
    m += (v == 0.0f);
    f += (v == 1.0f);
  }
  atomicAdd(&scnt[0], m);
  atomicAdd(&scnt[1], f);
  __syncthreads();
  if (threadIdx.x < 11) {
    atomicMax(&ws[MIN_OFF + threadIdx.x], smn[threadIdx.x]);
    atomicMax(&ws[MAX_OFF + threadIdx.x], smx[threadIdx.x]);
  }
  if (threadIdx.x == 11) atomicAdd(&ws[CNT_OFF + 0], scnt[0]);
  if (threadIdx.x == 12) atomicAdd(&ws[CNT_OFF + 1], scnt[1]);
}

// gendered histograms, male packed lo16 / female hi16 in per-block LDS hist
// (per-block per-bin count <= B/HBLK = 1024, fits 16 bits), merged into
// global MH/FH with skip-zero atomics. Element-linear grid-stride: lane i
// reads enc word i (fully coalesced); (r,c) updated incrementally.
__global__ __launch_bounds__(256) void k_hist(const float* __restrict__ enc,
                                              const float* __restrict__ lab,
                                              unsigned* __restrict__ ws, int B) {
  __shared__ unsigned h[2][NHCOLS * BINS];
  __shared__ float smn[NHCOLS], srng[NHCOLS];
  unsigned* hf = &h[0][0];
  for (int i = threadIdx.x; i < 2 * NHCOLS * BINS; i += blockDim.x) hf[i] = 0u;
  if (threadIdx.x < NHCOLS) {
    float lo = ord2f(~ws[MIN_OFF + threadIdx.x]);   // inverted-order min
    float hi = ord2f(ws[MAX_OFF + threadIdx.x]);
    smn[threadIdx.x] = lo;
    srng[threadIdx.x] = hi - lo;
  }
  __syncthreads();
  const int sub    = (threadIdx.x >> 6) & 1;
  const int total  = B * 11;
  const int stride = HBLK * 256;               // 65536
  const int qs     = stride / 11;              // uniform
  const int rs     = stride % 11;
  int i = blockIdx.x * 256 + threadIdx.x;
  int r = i / 11;                              // one div total
  int c = i - r * 11;
  for (; i < total; i += stride) {
    if (c < NHCOLS) {
      float lv = lab[r];
      unsigned add = (lv == 0.0f) ? 1u : ((lv == 1.0f) ? 0x10000u : 0u);
      if (add) {
        float t = (enc[i] - smn[c]) / srng[c]; // IEEE div, matches numpy
        int b = (int)floorf(t * 800.0f);
        b = b < 0 ? 0 : (b > BINS - 1 ? BINS - 1 : b);
        atomicAdd(&h[sub][c * BINS + b], add);
      }
    }
    r += qs; c += rs;
    if (c >= 11) { c -= 11; ++r; }
  }
  __syncthreads();
  for (int k = threadIdx.x; k < NHCOLS * BINS; k += blockDim.x) {
    unsigned v = h[0][k] + h[1][k];
    unsigned m = v & 0xFFFFu, f = v >> 16;
    if (m) atomicAdd(&ws[MH_OFF + k], m);
    if (f) atomicAdd(&ws[FH_OFF + k], f);
  }
}

// ---- column classification (compile-time) ----
__host__ __device__ constexpr int slice_of(int c) {
  return (c>=1&&c<10)?0:(c>=12&&c<29)?1:(c>=30&&c<33)?2:(c>=33&&c<40)?3:
         (c>=40&&c<64)?4:(c>=64&&c<79)?5:(c>=79&&c<84)?6:(c>=84&&c<94)?7:
         (c>=94&&c<96)?8:(c>=96&&c<99)?9:(c>=99&&c<105)?10:(c>=105&&c<113)?11:
         (c>=116&&c<122)?12:(c>=122&&c<128)?13:(c>=128&&c<151)?14:
         (c>=151&&c<159)?15:(c>=160&&c<165)?16:-1;
}
__host__ __device__ constexpr bool mse_of(int c) {
  return c==0||c==10||c==11||c==29||c==113||c==114||c==115||c==159||
         c==165||c==166||c==167;
}

// One register element (window I, sub-elem K). Lane j of the quad holds
// column 16I+4j+K; masks over j are compile-time -> branchless cndmask+add.
template<int I, int K>
__device__ __forceinline__ void elem(const f4 (&d)[11], const f4 (&t)[11],
                                     float (&s)[17], float &dot, float &mse, int j) {
  constexpr int c0 = 16*I + K, c1 = c0+4, c2 = c0+8, c3 = c0+12;
  constexpr int cem = ((c0<168 && slice_of(c0)>=0)?1:0) |
                      ((c1<168 && slice_of(c1)>=0)?2:0) |
                      ((c2<168 && slice_of(c2)>=0)?4:0) |
                      ((c3<168 && slice_of(c3)>=0)?8:0);
  constexpr int msm = ((c0<168 && mse_of(c0))?1:0) | ((c1<168 && mse_of(c1))?2:0) |
                      ((c2<168 && mse_of(c2))?4:0) | ((c3<168 && mse_of(c3))?8:0);
  const float dv = d[I][K], tv = t[I][K];
  if constexpr (cem != 0) {
    float e = __expf(dv);
    if constexpr (cem & 1) s[slice_of(c0)] += (j == 0) ? e : 0.0f;
    if constexpr (cem & 2) s[slice_of(c1)] += (j == 1) ? e : 0.0f;
    if constexpr (cem & 4) s[slice_of(c2)] += (j == 2) ? e : 0.0f;
    if constexpr (cem & 8) s[slice_of(c3)] += (j == 3) ? e : 0.0f;
    dot += ((cem >> j) & 1) ? tv * dv : 0.0f;
  }
  if constexpr (msm != 0) {
    float df = dv - tv;
    mse += ((msm >> j) & 1) ? df * df : 0.0f;
  }
}

template<int I>
__device__ __forceinline__ void elem_row(const f4 (&d)[11], const f4 (&t)[11],
                                         float (&s)[17], float &dot, float &mse, int j) {
  elem<I,0>(d, t, s, dot, mse, j);
  elem<I,1>(d, t, s, dot, mse, j);
  elem<I,2>(d, t, s, dot, mse, j);
  elem<I,3>(d, t, s, dot, mse, j);
}

// Two asm loads (window idx, byte offset off) off the shared bases.
#define LD2(idx, off)                                                          \
  asm volatile("global_load_dwordx4 %0, %1, off offset:" #off                  \
               : "=v"(dv[idx]) : "v"(baseD));                                  \
  asm volatile("global_load_dwordx4 %0, %1, off offset:" #off                  \
               : "=v"(tv[idx]) : "v"(baseT));

// Counted wait for window I (loads retire in issue order; window I's pair is
// retired once outstanding <= 20-2I), then pin just that window's registers
// so the consuming compute is ordered after the wait.
#define WAITPIN(idx, n)                                                        \
  asm volatile("s_waitcnt vmcnt(" #n ")" ::: "memory");                        \
  __builtin_amdgcn_sched_barrier(0);                                           \
  asm volatile("" : "+v"(dv[idx]), "+v"(tv[idx]));

// quad-per-row: lane j of the quad loads words 4i+j (64B contiguous per quad
// per window). All 22 loads are volatile inline-asm global_load_dwordx4:
// issued back-to-back, then compute is interleaved with counted vmcnt waits
// so window I's math runs while windows I+1..10 are still in flight.
__global__ __launch_bounds__(256, 2) void k_main(const float* __restrict__ dec,
                                                 const float* __restrict__ tru,
                                                 float* __restrict__ wsf, int B) {
  const int lane = threadIdx.x & 63;
  const int wid  = threadIdx.x >> 6;
  const int j    = lane & 3;
  const int row  = blockIdx.x * 64 + (wid << 4) + (lane >> 2);
  const bool valid = row < B;
  const int rowc = valid ? row : (B - 1);

  const float* baseD = dec + (size_t)rowc * 168 + 4 * j;
  const float* baseT = tru + (size_t)rowc * 168 + 4 * j;
  const int w10 = (40 + j) > 41 ? 41 : (40 + j);        // clamped last word
  const float* d10 = dec + (size_t)rowc * 168 + 4 * w10;
  const float* t10 = tru + (size_t)rowc * 168 + 4 * w10;

  // accumulators live before the loads so compute can start at first retire
  float s[17];
#pragma unroll
  for (int k = 0; k < 17; ++k) s[k] = 0.0f;
  float dot = 0.0f, mse = 0.0f;

  f4 dv[11], tv[11];
  LD2(0, 0)
  LD2(1, 64)
  LD2(2, 128)
  LD2(3, 192)
  LD2(4, 256)
  LD2(5, 320)
  LD2(6, 384)
  LD2(7, 448)
  LD2(8, 512)
  LD2(9, 576)
  asm volatile("global_load_dwordx4 %0, %1, off" : "=v"(dv[10]) : "v"(d10));
  asm volatile("global_load_dwordx4 %0, %1, off" : "=v"(tv[10]) : "v"(t10));

  WAITPIN(0, 20)  elem_row<0>(dv, tv, s, dot, mse, j);
  WAITPIN(1, 18)  elem_row<1>(dv, tv, s, dot, mse, j);
  WAITPIN(2, 16)  elem_row<2>(dv, tv, s, dot, mse, j);
  WAITPIN(3, 14)  elem_row<3>(dv, tv, s, dot, mse, j);
  WAITPIN(4, 12)  elem_row<4>(dv, tv, s, dot, mse, j);
  WAITPIN(5, 10)  elem_row<5>(dv, tv, s, dot, mse, j);
  WAITPIN(6, 8)   elem_row<6>(dv, tv, s, dot, mse, j);
  WAITPIN(7, 6)   elem_row<7>(dv, tv, s, dot, mse, j);
  WAITPIN(8, 4)   elem_row<8>(dv, tv, s, dot, mse, j);
  WAITPIN(9, 2)   elem_row<9>(dv, tv, s, dot, mse, j);
  WAITPIN(10, 0)  elem_row<10>(dv, tv, s, dot, mse, j);

  // quad allreduce: 34 + 2 independent shuffles
  dot += __shfl_xor(dot, 1, 64);
  dot += __shfl_xor(dot, 2, 64);
#pragma unroll
  for (int k = 0; k < 17; ++k) {
    s[k] += __shfl_xor(s[k], 1, 64);
    s[k] += __shfl_xor(s[k], 2, 64);
  }
  float ce = -dot;
#pragma unroll
  for (int k = 0; k < 17; ++k) ce += __logf(s[k]);

  // ce replicated across quad -> count once; mask invalid rows.
  ce  = (valid && j == 0) ? ce : 0.0f;
  mse = valid ? mse : 0.0f;

  __shared__ float sm[4], sc[4];
#pragma unroll
  for (int off = 32; off > 0; off >>= 1) {
    mse += __shfl_down(mse, off, 64);
    ce  += __shfl_down(ce, off, 64);
  }
  if (lane == 0) { sm[wid] = mse; sc[wid] = ce; }
  __syncthreads();
  if (threadIdx.x == 0) {
    const int slot = (blockIdx.x & 63) * 32;   // 128B-padded slots, 64-way spread
    atomicAdd(&wsf[SUM2_OFF + slot], sm[0] + sm[1] + sm[2] + sm[3]);
    atomicAdd(&wsf[SUM2_CE  + slot], sc[0] + sc[1] + sc[2] + sc[3]);
  }
}

__global__ __launch_bounds__(256) void k_final(const unsigned* __restrict__ ws,
                                               float* __restrict__ out, int B) {
  const float* wsf = (const float*)ws;
  float male   = (float)ws[CNT_OFF + 0];
  float female = (float)ws[CNT_OFF + 1];
  float local = 0.0f;
  for (int i = threadIdx.x; i < NHCOLS * BINS; i += blockDim.x) {
    float mh  = (float)ws[MH_OFF + i] / male;
    float fh  = (float)ws[FH_OFF + i] / female;
    float mid = 0.5f * (mh + fh);
    if (mh > 0.0f) local += mh * logf((mh + 1e-12f) / (mid + 1e-12f));
    if (fh > 0.0f) local += fh * logf((fh + 1e-12f) / (mid + 1e-12f));
  }
  int lane = threadIdx.x & 63, wid = threadIdx.x >> 6;
  // mse/ce staging slots: wave 0 reduces 64 slots in parallel
  float msep = 0.0f, cep = 0.0f;
  if (threadIdx.x < 64) {
    msep = wsf[SUM2_OFF + threadIdx.x * 32];
    cep  = wsf[SUM2_CE  + threadIdx.x * 32];
  }
  __shared__ float s[4], sm2, sc2;
#pragma unroll
  for (int off = 32; off > 0; off >>= 1) {
    local += __shfl_down(local, off, 64);
    msep  += __shfl_down(msep, off, 64);
    cep   += __shfl_down(cep, off, 64);
  }
  if (lane == 0) s[wid] = local;
  if (threadIdx.x == 0) { sm2 = msep; sc2 = cep; }
  __syncthreads();
  if (threadIdx.x == 0) {
    float kld   = 0.5f * (s[0] + s[1] + s[2] + s[3]);
    float mse   = sm2 / (float)B;
    float ce    = sc2 / (float)B;
    float multi = 0.9f * (mse + ce) + 0.1f * kld;
    out[0] = multi;
    out[1] = mse;
    out[2] = ce;
    out[3] = 0.1f * kld;
  }
}

extern "C" void kernel_launch(void* const* d_in, const int* in_sizes, int n_in,
                              void* d_out, int out_size, void* d_ws, size_t ws_size,
                              hipStream_t stream) {
  (void)n_in; (void)out_size; (void)ws_size;
  const float* enc = (const float*)d_in[0];
  const float* dec = (const float*)d_in[1];
  const float* tru = (const float*)d_in[2];
  const float* lab = (const float*)d_in[3];
  const int B = in_sizes[3];                 // label_true is [B,1]
  unsigned* ws = (unsigned*)d_ws;
  float* out = (float*)d_out;

  hipMemsetAsync(ws, 0, WS_TOTAL_U32 * 4, stream);
  hipLaunchKernelGGL(k_minmax, dim3(352), dim3(256), 0, stream, enc, lab, ws, B);
  hipLaunchKernelGGL(k_hist, dim3(HBLK), dim3(256), 0, stream, enc, lab, ws, B);
  hipLaunchKernelGGL(k_main, dim3((B + 63) / 64), dim3(256), 0, stream,
                     dec, tru, (float*)ws, B);
  hipLaunchKernelGGL(k_final, dim3(1), dim3(256), 0, stream, ws, out, B);
}

// Round 7
// 439.257 us; speedup vs baseline: 1.0332x; 1.0003x over previous
//
#include <hip/hip_runtime.h>
#include <math.h>

// ---------------------------------------------------------------------------
// MultiLoss + JSD fused pipeline. R11:
//  * k_main: OCCUPANCY, not schedule. Post-mortem of R6/R8/R9 (identical
//    118us across three schedule families) + unit fix: VGPR_Count is in
//    granules of 4 (52 -> 208 raw) => all variants ran 2-3 waves/SIMD
//    (occupancy 33-43%), too few waves to hide latency; the copy ubench
//    that hits 6.3 TB/s runs 8 waves/SIMD. R10's persistent pipeline
//    spilled in-flight asm load destinations -> NaN (spill store reads the
//    reg before the load lands). New design: 8-lane row groups (lane j
//    holds float4 words 8i+j, i=0..5) -> register tile 48 floats (was 88),
//    no inline asm (compiler's depth-5 pipeline is fine once TLP exists),
//    target ~90-100 VGPR -> 5 waves/SIMD. Per-row reduce: 3 shfl levels.
//  * rest unchanged from R9 (passed, absmax 0.0).
// ---------------------------------------------------------------------------

#define BINS 800
#define NHCOLS 10
#define HBLK 256          // histogram blocks (1 per CU)

// workspace layout (uint32 indices)
#define MIN_OFF 0         // 11 inverted-order maxes (== mins)
#define MAX_OFF 16        // 11 ordered-uint maxs
#define CNT_OFF 32        // male, female counts
#define MH_OFF  64        // 8000 merged male hist
#define FH_OFF  8064      // 8000 merged female hist
#define SUM2_OFF 16384    // 64 mse slots (stride 32) then 64 ce slots (stride 32)
#define SUM2_CE  (SUM2_OFF + 2048)
#define WS_TOTAL_U32 20480

typedef float f4 __attribute__((ext_vector_type(4)));

__device__ __forceinline__ unsigned f2ord(float f) {
  unsigned u = __float_as_uint(f);
  return (u & 0x80000000u) ? ~u : (u | 0x80000000u);
}
__device__ __forceinline__ float ord2f(unsigned e) {
  return __uint_as_float((e & 0x80000000u) ? (e & 0x7FFFFFFFu) : ~e);
}

// per-column min/max of data_encoded + male/female counts from label.
// MIN stored as atomicMax of ~f2ord(v): zero-initializable.
__global__ __launch_bounds__(256) void k_minmax(const float* __restrict__ enc,
                                                const float* __restrict__ lab,
                                                unsigned* __restrict__ ws, int B) {
  const int tid    = blockIdx.x * blockDim.x + threadIdx.x;
  const int stride = gridDim.x * blockDim.x;   // 352*256 = 90112 = 11*8192
  const int c      = tid % 11;
  unsigned mni = 0u, mx = 0u;                  // mni: max of inverted order
  const long long total = (long long)B * 11;
  for (long long i = tid; i < total; i += stride) {
    unsigned e = f2ord(enc[i]);
    unsigned ei = ~e;
    mni = mni > ei ? mni : ei;
    mx  = mx  > e  ? mx  : e;
  }
  __shared__ unsigned smn[11], smx[11], scnt[2];
  if (threadIdx.x < 11) { smn[threadIdx.x] = 0u; smx[threadIdx.x] = 0u; }
  if (threadIdx.x < 2)  scnt[threadIdx.x] = 0u;
  __syncthreads();
  atomicMax(&smn[c], mni);
  atomicMax(&smx[c], mx);
  unsigned m = 0, f = 0;
  for (int i = tid; i < B; i += stride) {
    float v = lab[i];
    m += (v == 0.0f);
    f += (v == 1.0f);
  }
  atomicAdd(&scnt[0], m);
  atomicAdd(&scnt[1], f);
  __syncthreads();
  if (threadIdx.x < 11) {
    atomicMax(&ws[MIN_OFF + threadIdx.x], smn[threadIdx.x]);
    atomicMax(&ws[MAX_OFF + threadIdx.x], smx[threadIdx.x]);
  }
  if (threadIdx.x == 11) atomicAdd(&ws[CNT_OFF + 0], scnt[0]);
  if (threadIdx.x == 12) atomicAdd(&ws[CNT_OFF + 1], scnt[1]);
}

// gendered histograms, male packed lo16 / female hi16 in per-block LDS hist
// (per-block per-bin count <= B/HBLK = 1024, fits 16 bits), merged into
// global MH/FH with skip-zero atomics. Element-linear grid-stride: lane i
// reads enc word i (fully coalesced); (r,c) updated incrementally.
__global__ __launch_bounds__(256) void k_hist(const float* __restrict__ enc,
                                              const float* __restrict__ lab,
                                              unsigned* __restrict__ ws, int B) {
  __shared__ unsigned h[2][NHCOLS * BINS];
  __shared__ float smn[NHCOLS], srng[NHCOLS];
  unsigned* hf = &h[0][0];
  for (int i = threadIdx.x; i < 2 * NHCOLS * BINS; i += blockDim.x) hf[i] = 0u;
  if (threadIdx.x < NHCOLS) {
    float lo = ord2f(~ws[MIN_OFF + threadIdx.x]);   // inverted-order min
    float hi = ord2f(ws[MAX_OFF + threadIdx.x]);
    smn[threadIdx.x] = lo;
    srng[threadIdx.x] = hi - lo;
  }
  __syncthreads();
  const int sub    = (threadIdx.x >> 6) & 1;
  const int total  = B * 11;
  const int stride = HBLK * 256;               // 65536
  const int qs     = stride / 11;              // uniform
  const int rs     = stride % 11;
  int i = blockIdx.x * 256 + threadIdx.x;
  int r = i / 11;                              // one div total
  int c = i - r * 11;
  for (; i < total; i += stride) {
    if (c < NHCOLS) {
      float lv = lab[r];
      unsigned add = (lv == 0.0f) ? 1u : ((lv == 1.0f) ? 0x10000u : 0u);
      if (add) {
        float t = (enc[i] - smn[c]) / srng[c]; // IEEE div, matches numpy
        int b = (int)floorf(t * 800.0f);
        b = b < 0 ? 0 : (b > BINS - 1 ? BINS - 1 : b);
        atomicAdd(&h[sub][c * BINS + b], add);
      }
    }
    r += qs; c += rs;
    if (c >= 11) { c -= 11; ++r; }
  }
  __syncthreads();
  for (int k = threadIdx.x; k < NHCOLS * BINS; k += blockDim.x) {
    unsigned v = h[0][k] + h[1][k];
    unsigned m = v & 0xFFFFu, f = v >> 16;
    if (m) atomicAdd(&ws[MH_OFF + k], m);
    if (f) atomicAdd(&ws[FH_OFF + k], f);
  }
}

// ---- column classification (compile-time) ----
__host__ __device__ constexpr int slice_of(int c) {
  return (c>=1&&c<10)?0:(c>=12&&c<29)?1:(c>=30&&c<33)?2:(c>=33&&c<40)?3:
         (c>=40&&c<64)?4:(c>=64&&c<79)?5:(c>=79&&c<84)?6:(c>=84&&c<94)?7:
         (c>=94&&c<96)?8:(c>=96&&c<99)?9:(c>=99&&c<105)?10:(c>=105&&c<113)?11:
         (c>=116&&c<122)?12:(c>=122&&c<128)?13:(c>=128&&c<151)?14:
         (c>=151&&c<159)?15:(c>=160&&c<165)?16:-1;
}
__host__ __device__ constexpr bool mse_of(int c) {
  return c==0||c==10||c==11||c==29||c==113||c==114||c==115||c==159||
         c==165||c==166||c==167;
}
// 8-bit lane masks for the 8-lane row-group layout: column of (base, lane j)
// is base + 4*j.
__host__ __device__ constexpr unsigned cem_of(int base) {
  unsigned m = 0;
  for (int jj = 0; jj < 8; ++jj) {
    int c = base + 4 * jj;
    if (c < 168 && slice_of(c) >= 0) m |= (1u << jj);
  }
  return m;
}
__host__ __device__ constexpr unsigned msm_of(int base) {
  unsigned m = 0;
  for (int jj = 0; jj < 8; ++jj) {
    int c = base + 4 * jj;
    if (c < 168 && mse_of(c)) m |= (1u << jj);
  }
  return m;
}

// One register element (window I, sub-elem K). Lane j of the 8-lane group
// holds column 32I+4j+K; masks over j are compile-time -> branchless adds.
template<int I, int K>
__device__ __forceinline__ void elem(const f4 (&d)[6], const f4 (&t)[6],
                                     float (&s)[17], float &dot, float &mse, int j) {
  constexpr int base = 32 * I + K;
  constexpr unsigned cem = cem_of(base);
  constexpr unsigned msm = msm_of(base);
  const float dv = d[I][K], tv = t[I][K];
  if constexpr (cem != 0) {
    float e = __expf(dv);
    if constexpr (cem & 1u)   s[slice_of(base + 0)]  += (j == 0) ? e : 0.0f;
    if constexpr (cem & 2u)   s[slice_of(base + 4)]  += (j == 1) ? e : 0.0f;
    if constexpr (cem & 4u)   s[slice_of(base + 8)]  += (j == 2) ? e : 0.0f;
    if constexpr (cem & 8u)   s[slice_of(base + 12)] += (j == 3) ? e : 0.0f;
    if constexpr (cem & 16u)  s[slice_of(base + 16)] += (j == 4) ? e : 0.0f;
    if constexpr (cem & 32u)  s[slice_of(base + 20)] += (j == 5) ? e : 0.0f;
    if constexpr (cem & 64u)  s[slice_of(base + 24)] += (j == 6) ? e : 0.0f;
    if constexpr (cem & 128u) s[slice_of(base + 28)] += (j == 7) ? e : 0.0f;
    dot += ((cem >> j) & 1u) ? tv * dv : 0.0f;
  }
  if constexpr (msm != 0) {
    float df = dv - tv;
    mse += ((msm >> j) & 1u) ? df * df : 0.0f;
  }
}

template<int I>
__device__ __forceinline__ void elem_row(const f4 (&d)[6], const f4 (&t)[6],
                                         float (&s)[17], float &dot, float &mse, int j) {
  elem<I,0>(d, t, s, dot, mse, j);
  elem<I,1>(d, t, s, dot, mse, j);
  elem<I,2>(d, t, s, dot, mse, j);
  elem<I,3>(d, t, s, dot, mse, j);
}

// 8-lane row groups: lane j of a group loads float4 words 8i+j (i=0..5),
// 128B contiguous per group per window. Window 5 clamps the word to
// min(40+j, 41): j>=2 is a duplicate whose columns (>=168) have
// compile-time-zero cem/msm masks -> never accumulated. Tile = 48 VGPRs
// (was 88), no inline asm: occupancy (not schedule) is the lever.
__global__ __launch_bounds__(256, 4) void k_main(const float* __restrict__ dec,
                                                 const float* __restrict__ tru,
                                                 float* __restrict__ wsf, int B) {
  const int lane = threadIdx.x & 63;
  const int wid  = threadIdx.x >> 6;
  const int j    = lane & 7;
  const int row  = blockIdx.x * 32 + (wid << 3) + (lane >> 3);
  const bool valid = row < B;
  const int rowc = valid ? row : (B - 1);

  const f4* d4 = (const f4*)(dec + (size_t)rowc * 168);
  const f4* t4 = (const f4*)(tru + (size_t)rowc * 168);
  const int w5 = (40 + j) > 41 ? 41 : (40 + j);

  f4 d[6], t[6];
#pragma unroll
  for (int i = 0; i < 5; ++i) {
    d[i] = d4[8 * i + j];
    t[i] = t4[8 * i + j];
  }
  d[5] = d4[w5];
  t[5] = t4[w5];

  float s[17];
#pragma unroll
  for (int k = 0; k < 17; ++k) s[k] = 0.0f;
  float dot = 0.0f, mse = 0.0f;

  elem_row<0>(d, t, s, dot, mse, j);
  elem_row<1>(d, t, s, dot, mse, j);
  elem_row<2>(d, t, s, dot, mse, j);
  elem_row<3>(d, t, s, dot, mse, j);
  elem_row<4>(d, t, s, dot, mse, j);
  elem_row<5>(d, t, s, dot, mse, j);

  // 8-lane-group allreduce: 3 levels, 17+1 values, independent shuffles
  dot += __shfl_xor(dot, 1, 64);
  dot += __shfl_xor(dot, 2, 64);
  dot += __shfl_xor(dot, 4, 64);
#pragma unroll
  for (int k = 0; k < 17; ++k) {
    s[k] += __shfl_xor(s[k], 1, 64);
    s[k] += __shfl_xor(s[k], 2, 64);
    s[k] += __shfl_xor(s[k], 4, 64);
  }
  float ce = -dot;
#pragma unroll
  for (int k = 0; k < 17; ++k) ce += __logf(s[k]);

  // ce replicated across the 8-lane group -> count once; mask invalid rows.
  ce  = (valid && j == 0) ? ce : 0.0f;
  mse = valid ? mse : 0.0f;

  __shared__ float sm[4], sc[4];
#pragma unroll
  for (int off = 32; off > 0; off >>= 1) {
    mse += __shfl_down(mse, off, 64);
    ce  += __shfl_down(ce, off, 64);
  }
  if (lane == 0) { sm[wid] = mse; sc[wid] = ce; }
  __syncthreads();
  if (threadIdx.x == 0) {
    const int slot = (blockIdx.x & 63) * 32;   // 128B-padded slots, 64-way spread
    atomicAdd(&wsf[SUM2_OFF + slot], sm[0] + sm[1] + sm[2] + sm[3]);
    atomicAdd(&wsf[SUM2_CE  + slot], sc[0] + sc[1] + sc[2] + sc[3]);
  }
}

__global__ __launch_bounds__(256) void k_final(const unsigned* __restrict__ ws,
                                               float* __restrict__ out, int B) {
  const float* wsf = (const float*)ws;
  float male   = (float)ws[CNT_OFF + 0];
  float female = (float)ws[CNT_OFF + 1];
  float local = 0.0f;
  for (int i = threadIdx.x; i < NHCOLS * BINS; i += blockDim.x) {
    float mh  = (float)ws[MH_OFF + i] / male;
    float fh  = (float)ws[FH_OFF + i] / female;
    float mid = 0.5f * (mh + fh);
    if (mh > 0.0f) local += mh * logf((mh + 1e-12f) / (mid + 1e-12f));
    if (fh > 0.0f) local += fh * logf((fh + 1e-12f) / (mid + 1e-12f));
  }
  int lane = threadIdx.x & 63, wid = threadIdx.x >> 6;
  // mse/ce staging slots: wave 0 reduces 64 slots in parallel
  float msep = 0.0f, cep = 0.0f;
  if (threadIdx.x < 64) {
    msep = wsf[SUM2_OFF + threadIdx.x * 32];
    cep  = wsf[SUM2_CE  + threadIdx.x * 32];
  }
  __shared__ float s[4], sm2, sc2;
#pragma unroll
  for (int off = 32; off > 0; off >>= 1) {
    local += __shfl_down(local, off, 64);
    msep  += __shfl_down(msep, off, 64);
    cep   += __shfl_down(cep, off, 64);
  }
  if (lane == 0) s[wid] = local;
  if (threadIdx.x == 0) { sm2 = msep; sc2 = cep; }
  __syncthreads();
  if (threadIdx.x == 0) {
    float kld   = 0.5f * (s[0] + s[1] + s[2] + s[3]);
    float mse   = sm2 / (float)B;
    float ce    = sc2 / (float)B;
    float multi = 0.9f * (mse + ce) + 0.1f * kld;
    out[0] = multi;
    out[1] = mse;
    out[2] = ce;
    out[3] = 0.1f * kld;
  }
}

extern "C" void kernel_launch(void* const* d_in, const int* in_sizes, int n_in,
                              void* d_out, int out_size, void* d_ws, size_t ws_size,
                              hipStream_t stream) {
  (void)n_in; (void)out_size; (void)ws_size;
  const float* enc = (const float*)d_in[0];
  const float* dec = (const float*)d_in[1];
  const float* tru = (const float*)d_in[2];
  const float* lab = (const float*)d_in[3];
  const int B = in_sizes[3];                 // label_true is [B,1]
  unsigned* ws = (unsigned*)d_ws;
  float* out = (float*)d_out;

  hipMemsetAsync(ws, 0, WS_TOTAL_U32 * 4, stream);
  hipLaunchKernelGGL(k_minmax, dim3(352), dim3(256), 0, stream, enc, lab, ws, B);
  hipLaunchKernelGGL(k_hist, dim3(HBLK), dim3(256), 0, stream, enc, lab, ws, B);
  hipLaunchKernelGGL(k_main, dim3((B + 31) / 32), dim3(256), 0, stream,
                     dec, tru, (float*)ws, B);
  hipLaunchKernelGGL(k_final, dim3(1), dim3(256), 0, stream, ws, out, B);
}